// Round 3
// baseline (100.459 us; speedup 1.0000x reference)
//
#include <hip/hip_runtime.h>

// ---------------------------------------------------------------------------
// TreeEncoder fused MFMA kernel, round 3.
//   Change vs round 2: kill scratch spills (110 MB of HBM writes!) by halving
//   peak register pressure — per-t gate math is done in two mi-pairs, with the
//   12 B-fragments re-read for the second pair (L1-resident, ~free).
//   Embedding gets the same mi-pair split.
// ---------------------------------------------------------------------------

typedef short bf16x8 __attribute__((ext_vector_type(8)));
typedef float f32x4  __attribute__((ext_vector_type(4)));

#define MFMA16(a, b, c) __builtin_amdgcn_mfma_f32_16x16x32_bf16((a), (b), (c), 0, 0, 0)

__device__ __forceinline__ unsigned short f2bf(float f) {
    return (unsigned short)((__float_as_uint(f) + 0x8000u) >> 16);
}

__device__ __forceinline__ float frcp(float x) { return __builtin_amdgcn_rcpf(x); }

__device__ __forceinline__ float fsigmoid(float x) {
    return frcp(1.0f + __expf(-x));
}

__device__ __forceinline__ float ftanh(float x) {
    x = fminf(fmaxf(x, -10.0f), 10.0f);
    float e = __expf(2.0f * x);
    return (e - 1.0f) * frcp(e + 1.0f);
}

// ---------------------------------------------------------------------------
// Prep: weights -> MFMA B-fragment bf16 layout in ws.
//   B-frag (16x16x32): lane l holds B[k][n], n = 16*t + (l&15),
//   k = 32*kk + 8*(l>>4) + e.  1KB blocks: [block][lane][16B].
//   ws map (bytes):
//     [0, 16384)       emb_W: block = t*2 + kk                      (t<8, kk<2)
//     [16384, 212992)  gates: block = (layer*8 + t)*12 + gate*4 + kk
// ---------------------------------------------------------------------------
__global__ void prep_frags(const float* __restrict__ embW,
                           const float* __restrict__ Wi,
                           const float* __restrict__ Wo,
                           const float* __restrict__ Wc,
                           char* __restrict__ ws) {
    int fb = blockIdx.x;          // 0..207
    int l  = threadIdx.x;         // 0..63
    int g  = l >> 4, c0 = l & 15;

    const float* src;
    int t, kk;
    size_t dst;
    if (fb < 16) {
        t = fb >> 1; kk = fb & 1;
        src = embW;                                   // [64][128]
        dst = (size_t)fb * 1024;
    } else {
        int r = fb - 16;                              // (layer*8+t)*12+gate*4+kk
        int layer = r / 96;
        int r2 = r % 96;
        t = r2 / 12;
        int r3 = r2 % 12;
        int gate = r3 >> 2;
        kk = r3 & 3;
        const float* Ws[3] = {Wi, Wo, Wc};
        src = Ws[gate] + (size_t)layer * 128 * 128;   // [128][128]
        dst = 16384 + (size_t)r * 1024;
    }

    bf16x8 v;
#pragma unroll
    for (int e = 0; e < 8; ++e) {
        int k   = kk * 32 + g * 8 + e;
        int col = t * 16 + c0;
        v[e] = (short)f2bf(src[(size_t)k * 128 + col]);
    }
    *reinterpret_cast<bf16x8*>(ws + dst + (size_t)l * 16) = v;
}

// ---------------------------------------------------------------------------
// Main fused kernel: 512 blocks x 256 threads; each wave owns 64 rows.
// ---------------------------------------------------------------------------
__global__ __launch_bounds__(256, 2) void tree_enc(
        const float* __restrict__ X,       // [131072][64]
        const float* __restrict__ emb_b,   // [128]
        const float* __restrict__ bWi, const float* __restrict__ bUi,
        const float* __restrict__ bWo, const float* __restrict__ bUo,
        const float* __restrict__ bWc, const float* __restrict__ bUc,
        const char*  __restrict__ frags,   // ws
        float* __restrict__ out) {         // [256][128]

    // per-wave transpose buffer; 136 = 128 + 8 pad (bank spread for A reads)
    __shared__ __align__(16) unsigned short hbuf[4][64][136];
    __shared__ float redbuf[4][128];

    const int tid = threadIdx.x;
    const int w   = tid >> 6;
    const int l   = tid & 63;
    const int g   = l >> 4;           // k-group
    const int c0  = l & 15;           // col within 16-tile / A row
    const int rowbase = blockIdx.x * 256 + w * 64;
    const int b  = blockIdx.x >> 1;   // 2 blocks per batch

    // ---------------- embedding: h0 = X @ embW + emb_b (mi-pairs) -------
    {
        const f32x4 z4 = {0.f, 0.f, 0.f, 0.f};
#pragma unroll
        for (int half = 0; half < 2; ++half) {
            bf16x8 afr[2][2];         // [mtile-in-pair][kk], K=64
#pragma unroll
            for (int m2 = 0; m2 < 2; ++m2) {
#pragma unroll
                for (int kk = 0; kk < 2; ++kk) {
                    int row = rowbase + (half * 2 + m2) * 16 + c0;
                    const float4* p = reinterpret_cast<const float4*>(
                            X + (size_t)row * 64 + kk * 32 + g * 8);
                    float4 v0 = p[0], v1 = p[1];
                    bf16x8 a;
                    a[0] = (short)f2bf(v0.x); a[1] = (short)f2bf(v0.y);
                    a[2] = (short)f2bf(v0.z); a[3] = (short)f2bf(v0.w);
                    a[4] = (short)f2bf(v1.x); a[5] = (short)f2bf(v1.y);
                    a[6] = (short)f2bf(v1.z); a[7] = (short)f2bf(v1.w);
                    afr[m2][kk] = a;
                }
            }
#pragma unroll
            for (int t = 0; t < 8; ++t) {
                f32x4 acc[2] = {z4, z4};
#pragma unroll
                for (int kk = 0; kk < 2; ++kk) {
                    bf16x8 bf = *reinterpret_cast<const bf16x8*>(
                            frags + ((size_t)(t * 2 + kk) * 64 + l) * 16);
#pragma unroll
                    for (int m2 = 0; m2 < 2; ++m2)
                        acc[m2] = MFMA16(afr[m2][kk], bf, acc[m2]);
                }
                float bias = emb_b[t * 16 + c0];
#pragma unroll
                for (int m2 = 0; m2 < 2; ++m2)
#pragma unroll
                    for (int r = 0; r < 4; ++r)
                        hbuf[w][(half * 2 + m2) * 16 + g * 4 + r][t * 16 + c0] =
                            f2bf(acc[m2][r] + bias);
            }
        }
    }

    // ---------------- 2 TreeLSTM layers ----------------
    float msum[8];
#pragma unroll
    for (int t = 0; t < 8; ++t) msum[t] = 0.f;

    const f32x4 z4 = {0.f, 0.f, 0.f, 0.f};
#pragma unroll
    for (int layer = 0; layer < 2; ++layer) {
        // A-fragments of h from LDS (wave-private slice; DS in-order per wave)
        bf16x8 A[4][4];
#pragma unroll
        for (int mi = 0; mi < 4; ++mi)
#pragma unroll
            for (int kk = 0; kk < 4; ++kk)
                A[mi][kk] = *reinterpret_cast<const bf16x8*>(
                        &hbuf[w][mi * 16 + c0][kk * 32 + g * 8]);

        const char* fW = frags + 16384 + (size_t)layer * 98304;
        const int bofs = layer * 128;

#pragma unroll
        for (int t = 0; t < 8; ++t) {
            const char* ft = fW + (size_t)t * 12288 + (size_t)l * 16;
            const int c = t * 16 + c0;
            const float Bi = bWi[bofs + c] + bUi[bofs + c];
            const float Bo = bWo[bofs + c] + bUo[bofs + c];
            const float Bc = bWc[bofs + c] + bUc[bofs + c];

            // two mi-pair passes; B-frag reload for pass 2 hits L1 (12 KB set)
#pragma unroll
            for (int half = 0; half < 2; ++half) {
                f32x4 ai[2] = {z4, z4};
                f32x4 ao[2] = {z4, z4};
                f32x4 ac[2] = {z4, z4};
#pragma unroll
                for (int kk = 0; kk < 4; ++kk) {
                    bf16x8 bi = *reinterpret_cast<const bf16x8*>(ft + (size_t)(0 + kk) * 1024);
                    bf16x8 bo = *reinterpret_cast<const bf16x8*>(ft + (size_t)(4 + kk) * 1024);
                    bf16x8 bc = *reinterpret_cast<const bf16x8*>(ft + (size_t)(8 + kk) * 1024);
#pragma unroll
                    for (int m2 = 0; m2 < 2; ++m2) {
                        const int mi = half * 2 + m2;
                        ai[m2] = MFMA16(A[mi][kk], bi, ai[m2]);
                        ao[m2] = MFMA16(A[mi][kk], bo, ao[m2]);
                        ac[m2] = MFMA16(A[mi][kk], bc, ac[m2]);
                    }
                }
#pragma unroll
                for (int m2 = 0; m2 < 2; ++m2) {
                    const int mi = half * 2 + m2;
#pragma unroll
                    for (int r = 0; r < 4; ++r) {
                        float iv = fsigmoid(ai[m2][r] + Bi);
                        float ov = fsigmoid(ao[m2][r] + Bo);
                        float cv = ftanh(ac[m2][r] + Bc);
                        float h  = ov * ftanh(iv * cv);
                        if (layer == 1) {
                            msum[t] += h;                   // mean partial
                        } else {
                            hbuf[w][mi * 16 + g * 4 + r][c] = f2bf(h);
                        }
                    }
                }
            }
        }
    }

    // ---------------- mean over nodes ----------------
#pragma unroll
    for (int t = 0; t < 8; ++t) {
        float v = msum[t];
        v += __shfl_xor(v, 16);
        v += __shfl_xor(v, 32);
        if (g == 0) redbuf[w][t * 16 + c0] = v;
    }
    __syncthreads();
    if (tid < 128) {
        float s = redbuf[0][tid] + redbuf[1][tid] + redbuf[2][tid] + redbuf[3][tid];
        atomicAdd(&out[b * 128 + tid], s * (1.0f / 512.0f));
    }
}

// ---------------------------------------------------------------------------
extern "C" void kernel_launch(void* const* d_in, const int* in_sizes, int n_in,
                              void* d_out, int out_size, void* d_ws, size_t ws_size,
                              hipStream_t stream) {
    const float* X    = (const float*)d_in[0];
    const float* embW = (const float*)d_in[1];
    const float* embb = (const float*)d_in[2];
    const float* Wi   = (const float*)d_in[3];
    const float* Wo   = (const float*)d_in[4];
    const float* Wc   = (const float*)d_in[5];
    const float* bWi  = (const float*)d_in[6];
    const float* bUi  = (const float*)d_in[7];
    const float* bWo  = (const float*)d_in[8];
    const float* bUo  = (const float*)d_in[9];
    const float* bWc  = (const float*)d_in[10];
    const float* bUc  = (const float*)d_in[11];
    float* out = (float*)d_out;
    char*  ws  = (char*)d_ws;

    hipMemsetAsync(d_out, 0, (size_t)out_size * sizeof(float), stream);
    prep_frags<<<208, 64, 0, stream>>>(embW, Wi, Wo, Wc, ws);
    tree_enc<<<512, 256, 0, stream>>>(X, embb, bWi, bUi, bWo, bUo, bWc, bUc,
                                      (const char*)ws, out);
}

// Round 4
// 71.552 us; speedup vs baseline: 1.4040x; 1.4040x over previous
//
#include <hip/hip_runtime.h>

// ---------------------------------------------------------------------------
// TreeEncoder fused MFMA kernel, round 4.
//   Round 2/3 lesson: __launch_bounds__(256,2) clamped VGPRs to 128 and the
//   64-row/wave tile spilled ~210 f32/thread to scratch (105 MB HBM writes).
//   Fix: back to 32 rows/wave (fits in ~144 VGPR, round-1-proven), plain
//   __launch_bounds__(256), and recover weight-traffic amortization via
//   block-wide double-buffered LDS staging of the per-t 12 KB B-fragment set
//   (issue-early / write-late).  Chip-wide weight traffic: 852 MB -> 106 MB.
// ---------------------------------------------------------------------------

typedef short bf16x8 __attribute__((ext_vector_type(8)));
typedef float f32x4  __attribute__((ext_vector_type(4)));

#define MFMA16(a, b, c) __builtin_amdgcn_mfma_f32_16x16x32_bf16((a), (b), (c), 0, 0, 0)

__device__ __forceinline__ unsigned short f2bf(float f) {
    return (unsigned short)((__float_as_uint(f) + 0x8000u) >> 16);
}

__device__ __forceinline__ float frcp(float x) { return __builtin_amdgcn_rcpf(x); }

__device__ __forceinline__ float fsigmoid(float x) {
    return frcp(1.0f + __expf(-x));
}

__device__ __forceinline__ float ftanh(float x) {
    x = fminf(fmaxf(x, -10.0f), 10.0f);
    float e = __expf(2.0f * x);
    return (e - 1.0f) * frcp(e + 1.0f);
}

// ---------------------------------------------------------------------------
// Prep: weights -> MFMA B-fragment bf16 layout in ws.
//   B-frag (16x16x32): lane l holds B[k][n], n = 16*t + (l&15),
//   k = 32*kk + 8*(l>>4) + e.  1KB blocks: [block][lane][16B].
//   ws map (bytes):
//     [0, 16384)       emb_W: block = t*2 + kk                      (t<8, kk<2)
//     [16384, 212992)  gates: block = (layer*8 + t)*12 + gate*4 + kk
// ---------------------------------------------------------------------------
__global__ void prep_frags(const float* __restrict__ embW,
                           const float* __restrict__ Wi,
                           const float* __restrict__ Wo,
                           const float* __restrict__ Wc,
                           char* __restrict__ ws) {
    int fb = blockIdx.x;          // 0..207
    int l  = threadIdx.x;         // 0..63
    int g  = l >> 4, c0 = l & 15;

    const float* src;
    int t, kk;
    size_t dst;
    if (fb < 16) {
        t = fb >> 1; kk = fb & 1;
        src = embW;                                   // [64][128]
        dst = (size_t)fb * 1024;
    } else {
        int r = fb - 16;                              // (layer*8+t)*12+gate*4+kk
        int layer = r / 96;
        int r2 = r % 96;
        t = r2 / 12;
        int r3 = r2 % 12;
        int gate = r3 >> 2;
        kk = r3 & 3;
        const float* Ws[3] = {Wi, Wo, Wc};
        src = Ws[gate] + (size_t)layer * 128 * 128;   // [128][128]
        dst = 16384 + (size_t)r * 1024;
    }

    bf16x8 v;
#pragma unroll
    for (int e = 0; e < 8; ++e) {
        int k   = kk * 32 + g * 8 + e;
        int col = t * 16 + c0;
        v[e] = (short)f2bf(src[(size_t)k * 128 + col]);
    }
    *reinterpret_cast<bf16x8*>(ws + dst + (size_t)l * 16) = v;
}

// ---------------------------------------------------------------------------
// Main fused kernel: 1024 blocks x 256 threads; each wave owns 32 rows.
// Weight fragments staged block-wide in LDS (double-buffered per t).
// ---------------------------------------------------------------------------
__global__ __launch_bounds__(256) void tree_enc(
        const float* __restrict__ X,       // [131072][64]
        const float* __restrict__ emb_b,   // [128]
        const float* __restrict__ bWi, const float* __restrict__ bUi,
        const float* __restrict__ bWo, const float* __restrict__ bUo,
        const float* __restrict__ bWc, const float* __restrict__ bUc,
        const char*  __restrict__ frags,   // ws
        float* __restrict__ out) {         // [256][128]

    // 34816 B transpose buffer + 24576 B weight staging + 2048 B reduce = 61440 B
    __shared__ __align__(16) unsigned short hbuf[4][32][136];
    __shared__ __align__(16) char sbuf[2][12288];
    __shared__ float redbuf[4][128];

    const int tid = threadIdx.x;
    const int w   = tid >> 6;
    const int l   = tid & 63;
    const int g   = l >> 4;           // k-group
    const int c0  = l & 15;           // col within 16-tile / A row
    const int rowbase = blockIdx.x * 128 + w * 32;
    const int b  = blockIdx.x >> 2;   // 4 blocks per batch

    // ---- stage embedding fragments (16 KB) into sbuf region ----
    {
        bf16x8 ev[4];
#pragma unroll
        for (int i = 0; i < 4; ++i)
            ev[i] = *reinterpret_cast<const bf16x8*>(frags + i * 4096 + tid * 16);
#pragma unroll
        for (int i = 0; i < 4; ++i)
            *reinterpret_cast<bf16x8*>(&sbuf[0][0] + i * 4096 + tid * 16) = ev[i];
    }
    __syncthreads();

    // ---------------- embedding: h0 = X @ embW + emb_b ----------------
    {
        bf16x8 afr[2][2];             // [mtile][kk], K=64
#pragma unroll
        for (int mi = 0; mi < 2; ++mi) {
#pragma unroll
            for (int kk = 0; kk < 2; ++kk) {
                int row = rowbase + mi * 16 + c0;
                const float4* p = reinterpret_cast<const float4*>(
                        X + (size_t)row * 64 + kk * 32 + g * 8);
                float4 v0 = p[0], v1 = p[1];
                bf16x8 a;
                a[0] = (short)f2bf(v0.x); a[1] = (short)f2bf(v0.y);
                a[2] = (short)f2bf(v0.z); a[3] = (short)f2bf(v0.w);
                a[4] = (short)f2bf(v1.x); a[5] = (short)f2bf(v1.y);
                a[6] = (short)f2bf(v1.z); a[7] = (short)f2bf(v1.w);
                afr[mi][kk] = a;
            }
        }
        const f32x4 z4 = {0.f, 0.f, 0.f, 0.f};
#pragma unroll
        for (int t = 0; t < 8; ++t) {
            f32x4 acc[2] = {z4, z4};
#pragma unroll
            for (int kk = 0; kk < 2; ++kk) {
                bf16x8 bf = *reinterpret_cast<const bf16x8*>(
                        &sbuf[0][0] + (size_t)(t * 2 + kk) * 1024 + l * 16);
#pragma unroll
                for (int mi = 0; mi < 2; ++mi)
                    acc[mi] = MFMA16(afr[mi][kk], bf, acc[mi]);
            }
            float bias = emb_b[t * 16 + c0];
#pragma unroll
            for (int mi = 0; mi < 2; ++mi)
#pragma unroll
                for (int r = 0; r < 4; ++r)
                    hbuf[w][mi * 16 + g * 4 + r][t * 16 + c0] =
                        f2bf(acc[mi][r] + bias);   // C layout: col=l&15, row=4*(l>>4)+r
        }
    }
    __syncthreads();   // all waves done reading emb frags from sbuf

    // ---------------- 2 TreeLSTM layers ----------------
    float msum[8];
#pragma unroll
    for (int t = 0; t < 8; ++t) msum[t] = 0.f;

    const f32x4 z4 = {0.f, 0.f, 0.f, 0.f};
#pragma unroll
    for (int layer = 0; layer < 2; ++layer) {
        // A-fragments of h from LDS (wave-private slice; DS in-order per wave)
        bf16x8 A[2][4];
#pragma unroll
        for (int mi = 0; mi < 2; ++mi)
#pragma unroll
            for (int kk = 0; kk < 4; ++kk)
                A[mi][kk] = *reinterpret_cast<const bf16x8*>(
                        &hbuf[w][mi * 16 + c0][kk * 32 + g * 8]);

        const char* fW = frags + 16384 + (size_t)layer * 98304;
        const int bofs = layer * 128;

        // prologue: stage t=0 fragment set (12 KB) into sbuf[0]
        {
            bf16x8 v[3];
#pragma unroll
            for (int i = 0; i < 3; ++i)
                v[i] = *reinterpret_cast<const bf16x8*>(fW + i * 4096 + tid * 16);
#pragma unroll
            for (int i = 0; i < 3; ++i)
                *reinterpret_cast<bf16x8*>(&sbuf[0][0] + i * 4096 + tid * 16) = v[i];
        }
        __syncthreads();

#pragma unroll
        for (int t = 0; t < 8; ++t) {
            // issue-early: next t's fragment loads (global -> regs)
            bf16x8 pre[3];
            if (t < 7) {
                const char* srcW = fW + (size_t)(t + 1) * 12288;
#pragma unroll
                for (int i = 0; i < 3; ++i)
                    pre[i] = *reinterpret_cast<const bf16x8*>(srcW + i * 4096 + tid * 16);
            }

            const char* ft = &sbuf[t & 1][0] + (size_t)l * 16;
            f32x4 ai[2] = {z4, z4};
            f32x4 ao[2] = {z4, z4};
            f32x4 ac[2] = {z4, z4};
#pragma unroll
            for (int kk = 0; kk < 4; ++kk) {
                bf16x8 bi = *reinterpret_cast<const bf16x8*>(ft + (size_t)(0 + kk) * 1024);
                bf16x8 bo = *reinterpret_cast<const bf16x8*>(ft + (size_t)(4 + kk) * 1024);
                bf16x8 bc = *reinterpret_cast<const bf16x8*>(ft + (size_t)(8 + kk) * 1024);
#pragma unroll
                for (int mi = 0; mi < 2; ++mi) {
                    ai[mi] = MFMA16(A[mi][kk], bi, ai[mi]);
                    ao[mi] = MFMA16(A[mi][kk], bo, ao[mi]);
                    ac[mi] = MFMA16(A[mi][kk], bc, ac[mi]);
                }
            }
            const int c = t * 16 + c0;
            const float Bi = bWi[bofs + c] + bUi[bofs + c];
            const float Bo = bWo[bofs + c] + bUo[bofs + c];
            const float Bc = bWc[bofs + c] + bUc[bofs + c];
#pragma unroll
            for (int mi = 0; mi < 2; ++mi) {
#pragma unroll
                for (int r = 0; r < 4; ++r) {
                    float iv = fsigmoid(ai[mi][r] + Bi);
                    float ov = fsigmoid(ao[mi][r] + Bo);
                    float cv = ftanh(ac[mi][r] + Bc);
                    float h  = ov * ftanh(iv * cv);
                    if (layer == 1) {
                        msum[t] += h;                   // mean partial
                    } else {
                        hbuf[w][mi * 16 + g * 4 + r][c] = f2bf(h);
                    }
                }
            }

            // write-late: park next t's fragments in the other buffer
            if (t < 7) {
                char* dstS = &sbuf[(t + 1) & 1][0];
#pragma unroll
                for (int i = 0; i < 3; ++i)
                    *reinterpret_cast<bf16x8*>(dstS + i * 4096 + tid * 16) = pre[i];
            }
            __syncthreads();
        }
    }

    // ---------------- mean over nodes ----------------
#pragma unroll
    for (int t = 0; t < 8; ++t) {
        float v = msum[t];
        v += __shfl_xor(v, 16);
        v += __shfl_xor(v, 32);
        if (g == 0) redbuf[w][t * 16 + c0] = v;
    }
    __syncthreads();
    if (tid < 128) {
        float s = redbuf[0][tid] + redbuf[1][tid] + redbuf[2][tid] + redbuf[3][tid];
        atomicAdd(&out[b * 128 + tid], s * (1.0f / 512.0f));
    }
}

// ---------------------------------------------------------------------------
extern "C" void kernel_launch(void* const* d_in, const int* in_sizes, int n_in,
                              void* d_out, int out_size, void* d_ws, size_t ws_size,
                              hipStream_t stream) {
    const float* X    = (const float*)d_in[0];
    const float* embW = (const float*)d_in[1];
    const float* embb = (const float*)d_in[2];
    const float* Wi   = (const float*)d_in[3];
    const float* Wo   = (const float*)d_in[4];
    const float* Wc   = (const float*)d_in[5];
    const float* bWi  = (const float*)d_in[6];
    const float* bUi  = (const float*)d_in[7];
    const float* bWo  = (const float*)d_in[8];
    const float* bUo  = (const float*)d_in[9];
    const float* bWc  = (const float*)d_in[10];
    const float* bUc  = (const float*)d_in[11];
    float* out = (float*)d_out;
    char*  ws  = (char*)d_ws;

    hipMemsetAsync(d_out, 0, (size_t)out_size * sizeof(float), stream);
    prep_frags<<<208, 64, 0, stream>>>(embW, Wi, Wo, Wc, ws);
    tree_enc<<<1024, 256, 0, stream>>>(X, embb, bWi, bUi, bWo, bUo, bWc, bUc,
                                       (const char*)ws, out);
}